// Round 5
// baseline (233.963 us; speedup 1.0000x reference)
//
#include <hip/hip_runtime.h>

#define DIM 4096
#define HAD_SCALE 0.015625f  // 1/sqrt(4096) = 1/64

// DPP quad_perm lane shuffle (VALU pipe). 0xB1 = lane^1, 0x4E = lane^2.
template <int CTRL>
__device__ __forceinline__ float qperm(float v) {
    return __int_as_float(
        __builtin_amdgcn_mov_dpp(__float_as_int(v), CTRL, 0xF, 0xF, false));
}

// ds_swizzle bit-mode lane xor (LDS pipe, no LDS storage). offset encoding:
// (xor<<10)|(or<<5)|and, and=0x1F. xor4=0x101F, xor8=0x201F, xor16=0x401F.
template <int OFS>
__device__ __forceinline__ float lswz(float v) {
    return __int_as_float(
        __builtin_amdgcn_ds_swizzle(__float_as_int(v), OFS));
}

struct Signs { float sA, sB, sC, sD, sE, sF; };

// ---- verified-bit-exact row pipeline pieces (identical math to round 4,
// which measured absmax = 0.0) ----

__device__ __forceinline__ void loadRow(const float4* __restrict__ x4,
                                        int lane, float r[64]) {
#pragma unroll
    for (int g = 0; g < 16; g++) {
        float4 v = x4[g * 64 + lane];
        r[4 * g + 0] = v.x;
        r[4 * g + 1] = v.y;
        r[4 * g + 2] = v.z;
        r[4 * g + 3] = v.w;
    }
}

// Bit schedule (12 j-bits, each exactly once), j = e + 4*lane + 256*g:
//   in-register fwht        : bits {0,1}   (e)
//   DPP quad_perm xor1/xor2 : bits {2,3}   (lane bits 0,1)
//   ds_swizzle xor4/8/16    : bits {4,5,6} (lane bits 2,3,4)
//   shfl_xor 32             : bit  {7}     (lane bit 5)
//   in-register fwht        : bits {8..11} (g)
__device__ __forceinline__ void computeRow(float r[64], const Signs& s) {
#pragma unroll
    for (int g = 0; g < 16; g++) {
        {   // bits {0,1}: 2x2 fwht within the float4
            float a = r[4 * g + 0], b = r[4 * g + 1];
            float c = r[4 * g + 2], d = r[4 * g + 3];
            float ab0 = a + b, ab1 = a - b;
            float cd0 = c + d, cd1 = c - d;
            r[4 * g + 0] = ab0 + cd0;
            r[4 * g + 1] = ab1 + cd1;
            r[4 * g + 2] = ab0 - cd0;
            r[4 * g + 3] = ab1 - cd1;
        }
#pragma unroll
        for (int e = 0; e < 4; e++) {   // bits {2..7}: cross-lane chain
            float v = r[4 * g + e];
            v = __builtin_fmaf(v, s.sA, qperm<0xB1>(v));        // j bit 2
            v = __builtin_fmaf(v, s.sB, qperm<0x4E>(v));        // j bit 3
            v = __builtin_fmaf(v, s.sC, lswz<0x101F>(v));       // j bit 4
            v = __builtin_fmaf(v, s.sD, lswz<0x201F>(v));       // j bit 5
            v = __builtin_fmaf(v, s.sE, lswz<0x401F>(v));       // j bit 6
            v = __builtin_fmaf(v, s.sF, __shfl_xor(v, 32, 64)); // j bit 7
            r[4 * g + e] = v;
        }
    }
    // bits {8..11}: fwht over the group index (static indices only)
#pragma unroll
    for (int st = 4; st < 64; st <<= 1) {
#pragma unroll
        for (int i = 0; i < 64; i++) {
            if ((i & st) == 0) {
                float a = r[i];
                float b = r[i ^ st];
                r[i]      = a + b;
                r[i ^ st] = a - b;
            }
        }
    }
}

__device__ __forceinline__ void storeRow(float4* __restrict__ y4,
                                         int lane, const float r[64]) {
#pragma unroll
    for (int g = 0; g < 16; g++)
        y4[g * 64 + lane] = make_float4(r[4 * g + 0] * HAD_SCALE,
                                        r[4 * g + 1] * HAD_SCALE,
                                        r[4 * g + 2] * HAD_SCALE,
                                        r[4 * g + 3] * HAD_SCALE);
}

// ONE WAVE PER ROW, TWO ROWS PER WAVE, software-pipelined:
//   issue loads(A); issue loads(B)   -> 32 KiB in flight per wave
//   compute A  (B's loads stream in underneath)
//   store A    (fire-and-forget)
//   compute B  (A's stores drain underneath)
//   store B
// This keeps the memory system busy during every compute window — the
// phase-convoy (all waves load / all waves compute in lockstep) is what
// held rounds 0-4 at ~80 us / 2.4 TB/s.
// Block = 4 independent waves (4 rows), no barriers, no LDS storage.
__global__ __launch_bounds__(256) void fwht_kernel(const float* __restrict__ x,
                                                   float* __restrict__ y,
                                                   int nwaves) {
    const int t = threadIdx.x;
    const int lane = t & 63;
    const int wid = blockIdx.x * 4 + (t >> 6);   // 0..nwaves-1

    const size_t rowA = (size_t)wid;
    const size_t rowB = (size_t)wid + (size_t)nwaves;  // second pass over rows
    const float4* __restrict__ xA = (const float4*)(x + rowA * DIM);
    const float4* __restrict__ xB = (const float4*)(x + rowB * DIM);
    float4* __restrict__ yA = (float4*)(y + rowA * DIM);
    float4* __restrict__ yB = (float4*)(y + rowB * DIM);

    Signs s;
    s.sA = (lane & 1)  ? -1.f : 1.f;
    s.sB = (lane & 2)  ? -1.f : 1.f;
    s.sC = (lane & 4)  ? -1.f : 1.f;
    s.sD = (lane & 8)  ? -1.f : 1.f;
    s.sE = (lane & 16) ? -1.f : 1.f;
    s.sF = (lane & 32) ? -1.f : 1.f;

    float rA[64], rB[64];
    loadRow(xA, lane, rA);   // 16 outstanding dwordx4
    loadRow(xB, lane, rB);   // +16 more: 32 KiB in flight
    computeRow(rA, s);       // waits only on A's loads (vmcnt(16))
    storeRow(yA, lane, rA);  // A's registers die here
    computeRow(rB, s);       // B landed during computeRow(rA)
    storeRow(yB, lane, rB);
}

extern "C" void kernel_launch(void* const* d_in, const int* in_sizes, int n_in,
                              void* d_out, int out_size, void* d_ws, size_t ws_size,
                              hipStream_t stream) {
    const float* x = (const float*)d_in[0];
    float* y = (float*)d_out;
    const int n = in_sizes[0];
    const int rows = n / DIM;        // 8192 for (4, 2048, 4096)
    const int nwaves = rows / 2;     // 4096 waves, 2 rows each
    fwht_kernel<<<nwaves / 4, 256, 0, stream>>>(x, y, nwaves);
}